// Round 4
// baseline (638.629 us; speedup 1.0000x reference)
//
#include <hip/hip_runtime.h>
#include <stdint.h>
#include <math.h>

#define NUM_TOK 8192
#define DM 512
#define NE 8
#define NH 2048
#define MAX_TILES 72   // ceil-sum of per-expert 128-row tiles <= 64 + 7
#define KSPLIT 4       // ffn2 K-split (NH/KSPLIT = 512 per split)

typedef float f32x4 __attribute__((ext_vector_type(4)));
typedef __bf16 bf16x8 __attribute__((ext_vector_type(8)));

// ws layout (bytes)
#define WS_COUNTS   0                 // int[8]
#define WS_CURSORS  32                // int[8]
#define WS_OFFSETS  64                // int[8]
#define WS_IMP      96                // float[8]
#define WS_TILE_E   128               // int[72]
#define WS_TILE_R0  416               // int[72]
#define WS_EXP      704               // int[8192]
#define WS_WTOK     33472             // float[8192]
#define WS_PERM     66240             // int[8192]
#define WS_XG       99008             // bf16 (8192+128) x 512
#define WS_H        8618688           // bf16 (8192+128) x 2048
#define WS_W1T      42697408          // bf16 [8][2048][512]  = 16 MB
#define WS_W2T      59474624          // bf16 [8][512][2048]  = 16 MB -> ends 76,251,840

__device__ __forceinline__ uint16_t f2bf(float f) {
  union { float f; uint32_t u; } c; c.f = f;
  return (uint16_t)((c.u + 0x7FFFu + ((c.u >> 16) & 1u)) >> 16);
}

// ---------------- router: logits (fp64), gumbel argmax, weight, counts, importance ----------------
__global__ __launch_bounds__(64) void k_router(
    const float* __restrict__ x, const float* __restrict__ u,
    const float* __restrict__ rw, const float* __restrict__ rb,
    int* __restrict__ counts, float* __restrict__ imp,
    int* __restrict__ expert_of, float* __restrict__ wtok)
{
  __shared__ float s_rw[DM * NE];
  int tid = threadIdx.x;
  for (int i = tid; i < DM * NE / 4; i += 64)
    ((float4*)s_rw)[i] = ((const float4*)rw)[i];
  __syncthreads();

  int t = blockIdx.x * 64 + tid;
  double acc[NE];
  #pragma unroll
  for (int e = 0; e < NE; ++e) acc[e] = 0.0;
  const float* xr = x + (size_t)t * DM;
  for (int d4 = 0; d4 < DM / 4; ++d4) {
    float4 xv4 = ((const float4*)xr)[d4];
    #pragma unroll
    for (int c = 0; c < 4; ++c) {
      int d = d4 * 4 + c;
      double xv = (double)((c == 0) ? xv4.x : (c == 1) ? xv4.y : (c == 2) ? xv4.z : xv4.w);
      float4 r0 = ((const float4*)s_rw)[d * 2];
      float4 r1 = ((const float4*)s_rw)[d * 2 + 1];
      acc[0] += xv * (double)r0.x;
      acc[1] += xv * (double)r0.y;
      acc[2] += xv * (double)r0.z;
      acc[3] += xv * (double)r0.w;
      acc[4] += xv * (double)r1.x;
      acc[5] += xv * (double)r1.y;
      acc[6] += xv * (double)r1.z;
      acc[7] += xv * (double)r1.w;
    }
  }
  double lg[NE];
  #pragma unroll
  for (int e = 0; e < NE; ++e) lg[e] = acc[e] + (double)rb[e];

  // gumbel-perturbed argmax (first max wins, matching jnp.argmax)
  double ybest = -1e300; int sel = 0;
  double y[NE];
  #pragma unroll
  for (int e = 0; e < NE; ++e) {
    double uv = (double)u[t * NE + e];
    double g = -log(-log(uv) + 1e-10);
    y[e] = lg[e] + g;
    if (y[e] > ybest) { ybest = y[e]; sel = e; }
  }
  double s = 0.0;
  #pragma unroll
  for (int e = 0; e < NE; ++e) s += exp(y[e] - ybest);
  double p = 1.0 / s;                    // y_soft at the selected expert
  float w = (float)((1.0 - p) + p);      // hard - sg(y_soft) + y_soft, selected entry

  expert_of[t] = sel;
  wtok[t] = w;
  atomicAdd(&counts[sel], 1);

  // softmax(logits) for importance (aux loss)
  double lm = lg[0];
  #pragma unroll
  for (int e = 1; e < NE; ++e) lm = fmax(lm, lg[e]);
  double ss = 0.0; double pr[NE];
  #pragma unroll
  for (int e = 0; e < NE; ++e) { pr[e] = exp(lg[e] - lm); ss += pr[e]; }
  double inv = 1.0 / ss;
  #pragma unroll
  for (int e = 0; e < NE; ++e) {
    float v = (float)(pr[e] * inv);
    #pragma unroll
    for (int off = 32; off; off >>= 1) v += __shfl_xor(v, off, 64);
    if (tid == 0) atomicAdd(&imp[e], v);
  }
}

// ---------------- offsets + aux loss + compact tile table ----------------
__global__ void k_aux_offsets(const int* __restrict__ counts, const float* __restrict__ imp,
                              int* __restrict__ offsets, float* __restrict__ aux_out,
                              int* __restrict__ tile_e, int* __restrict__ tile_r0)
{
  if (threadIdx.x == 0) {
    int o = 0;
    for (int e = 0; e < NE; ++e) { offsets[e] = o; o += counts[e]; }
    float a = 0.0f;
    for (int e = 0; e < NE; ++e) {
      float dv = imp[e] / 8192.0f - 0.125f;
      a += dv * dv;
    }
    aux_out[0] = a / 8.0f;
    int nt = 0;
    for (int e = 0; e < NE; ++e) {
      int ntile = (counts[e] + 127) >> 7;
      for (int j = 0; j < ntile; ++j) {
        tile_e[nt] = e;
        tile_r0[nt] = offsets[e] + j * 128;
        ++nt;
      }
    }
    for (int i = nt; i < MAX_TILES; ++i) { tile_e[i] = -1; tile_r0[i] = 0; }
  }
}

// ---------------- counting-sort scatter: perm[pos] = token ----------------
__global__ __launch_bounds__(256) void k_scatter(
    const int* __restrict__ expert_of, const int* __restrict__ offsets,
    int* __restrict__ cursors, int* __restrict__ perm)
{
  int t = blockIdx.x * 256 + threadIdx.x;
  int e = expert_of[t];
  int pos = offsets[e] + atomicAdd(&cursors[e], 1);
  perm[pos] = t;
}

// ---------------- gather x rows into sorted bf16 Xg ----------------
__global__ __launch_bounds__(64) void k_gather(
    const float* __restrict__ x, const int* __restrict__ perm, uint16_t* __restrict__ Xg)
{
  int r = blockIdx.x;
  int lane = threadIdx.x;
  int t = perm[r];
  const float4* src = (const float4*)(x + (size_t)t * DM);
  float4 a = src[lane * 2];
  float4 b = src[lane * 2 + 1];
  uint32_t p0 = (uint32_t)f2bf(a.x) | ((uint32_t)f2bf(a.y) << 16);
  uint32_t p1 = (uint32_t)f2bf(a.z) | ((uint32_t)f2bf(a.w) << 16);
  uint32_t p2 = (uint32_t)f2bf(b.x) | ((uint32_t)f2bf(b.y) << 16);
  uint32_t p3 = (uint32_t)f2bf(b.z) | ((uint32_t)f2bf(b.w) << 16);
  uint4 v = make_uint4(p0, p1, p2, p3);
  ((uint4*)(Xg + (size_t)r * DM))[lane] = v;
}

// ---------------- weight transpose+convert: src [e][K][N] f32 -> dst [e][N][K] bf16 ----------------
__global__ __launch_bounds__(256) void k_transpose_bf16(
    const float* __restrict__ src, uint16_t* __restrict__ dst, int K, int N)
{
  __shared__ float T[64][65];
  int e = blockIdx.z;
  const float* s = src + (size_t)e * K * N;
  uint16_t* d = dst + (size_t)e * K * N;
  int n0 = blockIdx.x * 64, k0 = blockIdx.y * 64;
  int tid = threadIdx.x;
  int tr = tid >> 4;
  int tc = (tid & 15) * 4;
  #pragma unroll
  for (int p = 0; p < 4; ++p) {
    int k = tr + p * 16;
    float4 v = *(const float4*)(s + (size_t)(k0 + k) * N + n0 + tc);
    T[k][tc] = v.x; T[k][tc + 1] = v.y; T[k][tc + 2] = v.z; T[k][tc + 3] = v.w;
  }
  __syncthreads();
  #pragma unroll
  for (int p = 0; p < 2; ++p) {
    int slot = p * 256 + tid;
    int n = slot >> 3;
    int c = (slot & 7) * 8;
    uint16_t tmp[8];
    #pragma unroll
    for (int j = 0; j < 8; ++j) tmp[j] = f2bf(T[c + j][n]);
    *(uint4*)(d + (size_t)(n0 + n) * K + k0 + c) = *(uint4*)tmp;
  }
}

// ---------------- layer 1: h = gelu(Xg @ w1t[e]^T + b1[e]) ----------------
// grid (MAX_TILES, 16); compact tile table; 1-deep register prefetch
__global__ __launch_bounds__(256) void k_ffn1(
    const uint16_t* __restrict__ Xg, const uint16_t* __restrict__ w1t,
    const float* __restrict__ b1,
    const int* __restrict__ offsets, const int* __restrict__ counts,
    const int* __restrict__ tile_e, const int* __restrict__ tile_r0,
    uint16_t* __restrict__ hbuf)
{
  int e = tile_e[blockIdx.x];
  if (e < 0) return;
  int row0 = tile_r0[blockIdx.x];
  int row_end = offsets[e] + counts[e];
  int n0 = blockIdx.y * 128;
  const uint16_t* Bt = w1t + (size_t)e * DM * NH;   // [2048][512] bf16

  __shared__ uint16_t As[128 * 72];
  __shared__ uint16_t Bs[128 * 72];

  int tid = threadIdx.x;
  int lane = tid & 63, wid = tid >> 6;
  int wm = wid >> 1, wn = wid & 1;
  int l16 = lane & 15, quad = lane >> 4;

  int srow[4], skc[4];
  const uint16_t *pa[4], *pb[4];
  uint16_t *la[4], *lb[4];
  #pragma unroll
  for (int it = 0; it < 4; ++it) {
    int idx = it * 256 + tid;
    srow[it] = idx >> 3; skc[it] = (idx & 7) << 3;
    pa[it] = Xg + (size_t)(row0 + srow[it]) * DM + skc[it];
    pb[it] = Bt + (size_t)(n0 + srow[it]) * DM + skc[it];
    la[it] = As + srow[it] * 72 + skc[it];
    lb[it] = Bs + srow[it] * 72 + skc[it];
  }

  f32x4 acc[4][4] = {};
  uint4 ra[4], rb[4];
  #pragma unroll
  for (int it = 0; it < 4; ++it) {
    ra[it] = *(const uint4*)pa[it]; pa[it] += 64;
    rb[it] = *(const uint4*)pb[it]; pb[it] += 64;
  }

  #pragma unroll
  for (int k0 = 0; k0 < DM; k0 += 64) {
    #pragma unroll
    for (int it = 0; it < 4; ++it) {
      *(uint4*)la[it] = ra[it];
      *(uint4*)lb[it] = rb[it];
    }
    if (k0 + 64 < DM) {
      #pragma unroll
      for (int it = 0; it < 4; ++it) {
        ra[it] = *(const uint4*)pa[it]; pa[it] += 64;
        rb[it] = *(const uint4*)pb[it]; pb[it] += 64;
      }
    }
    __syncthreads();
    #pragma unroll
    for (int ks = 0; ks < 2; ++ks) {
      bf16x8 a[4], b[4];
      #pragma unroll
      for (int mi = 0; mi < 4; ++mi)
        a[mi] = *(const bf16x8*)(As + (wm * 64 + mi * 16 + l16) * 72 + ks * 32 + quad * 8);
      #pragma unroll
      for (int ni = 0; ni < 4; ++ni)
        b[ni] = *(const bf16x8*)(Bs + (wn * 64 + ni * 16 + l16) * 72 + ks * 32 + quad * 8);
      #pragma unroll
      for (int mi = 0; mi < 4; ++mi)
        #pragma unroll
        for (int ni = 0; ni < 4; ++ni)
          acc[mi][ni] = __builtin_amdgcn_mfma_f32_16x16x32_bf16(a[mi], b[ni], acc[mi][ni], 0, 0, 0);
    }
    __syncthreads();
  }

  #pragma unroll
  for (int ni = 0; ni < 4; ++ni) {
    int col = n0 + wn * 64 + ni * 16 + l16;
    float bv = b1[e * NH + col];
    #pragma unroll
    for (int mi = 0; mi < 4; ++mi) {
      int rbase = wm * 64 + mi * 16 + quad * 4;
      #pragma unroll
      for (int r = 0; r < 4; ++r) {
        int grow = row0 + rbase + r;
        if (grow < row_end) {
          float v = acc[mi][ni][r] + bv;
          float gl = 0.5f * v * (1.0f + erff(v * 0.70710678118654752440f));
          hbuf[(size_t)grow * NH + col] = f2bf(gl);
        }
      }
    }
  }
}

// ---------------- layer 2 (split-K): atomicAdd partials of (h @ w2t^T) * wtok into zeroed out ----------------
// grid (MAX_TILES, 4, KSPLIT)
__global__ __launch_bounds__(256) void k_ffn2(
    const uint16_t* __restrict__ hbuf, const uint16_t* __restrict__ w2t,
    const float* __restrict__ b2,
    const int* __restrict__ offsets, const int* __restrict__ counts,
    const int* __restrict__ tile_e, const int* __restrict__ tile_r0,
    const int* __restrict__ perm, const float* __restrict__ wtok,
    float* __restrict__ out)
{
  int e = tile_e[blockIdx.x];
  if (e < 0) return;
  int row0 = tile_r0[blockIdx.x];
  int row_end = offsets[e] + counts[e];
  int n0 = blockIdx.y * 128;
  int kc = blockIdx.z;
  int kbeg = kc * (NH / KSPLIT);
  int kend = kbeg + NH / KSPLIT;
  const uint16_t* Bt = w2t + (size_t)e * NH * DM;   // [512][2048] bf16

  __shared__ uint16_t As[128 * 72];
  __shared__ uint16_t Bs[128 * 72];

  int tid = threadIdx.x;
  int lane = tid & 63, wid = tid >> 6;
  int wm = wid >> 1, wn = wid & 1;
  int l16 = lane & 15, quad = lane >> 4;

  int srow[4], skc[4];
  const uint16_t *pa[4], *pb[4];
  uint16_t *la[4], *lb[4];
  #pragma unroll
  for (int it = 0; it < 4; ++it) {
    int idx = it * 256 + tid;
    srow[it] = idx >> 3; skc[it] = (idx & 7) << 3;
    pa[it] = hbuf + (size_t)(row0 + srow[it]) * NH + kbeg + skc[it];
    pb[it] = Bt + (size_t)(n0 + srow[it]) * NH + kbeg + skc[it];
    la[it] = As + srow[it] * 72 + skc[it];
    lb[it] = Bs + srow[it] * 72 + skc[it];
  }

  f32x4 acc[4][4] = {};
  uint4 ra[4], rb[4];
  #pragma unroll
  for (int it = 0; it < 4; ++it) {
    ra[it] = *(const uint4*)pa[it]; pa[it] += 64;
    rb[it] = *(const uint4*)pb[it]; pb[it] += 64;
  }

  #pragma unroll
  for (int k0 = 0; k0 < NH / KSPLIT; k0 += 64) {
    #pragma unroll
    for (int it = 0; it < 4; ++it) {
      *(uint4*)la[it] = ra[it];
      *(uint4*)lb[it] = rb[it];
    }
    if (k0 + 64 < NH / KSPLIT) {
      #pragma unroll
      for (int it = 0; it < 4; ++it) {
        ra[it] = *(const uint4*)pa[it]; pa[it] += 64;
        rb[it] = *(const uint4*)pb[it]; pb[it] += 64;
      }
    }
    __syncthreads();
    #pragma unroll
    for (int ks = 0; ks < 2; ++ks) {
      bf16x8 a[4], b[4];
      #pragma unroll
      for (int mi = 0; mi < 4; ++mi)
        a[mi] = *(const bf16x8*)(As + (wm * 64 + mi * 16 + l16) * 72 + ks * 32 + quad * 8);
      #pragma unroll
      for (int ni = 0; ni < 4; ++ni)
        b[ni] = *(const bf16x8*)(Bs + (wn * 64 + ni * 16 + l16) * 72 + ks * 32 + quad * 8);
      #pragma unroll
      for (int mi = 0; mi < 4; ++mi)
        #pragma unroll
        for (int ni = 0; ni < 4; ++ni)
          acc[mi][ni] = __builtin_amdgcn_mfma_f32_16x16x32_bf16(a[mi], b[ni], acc[mi][ni], 0, 0, 0);
    }
    __syncthreads();
  }

  #pragma unroll
  for (int ni = 0; ni < 4; ++ni) {
    int col = n0 + wn * 64 + ni * 16 + l16;
    float bv = (kc == 0) ? b2[e * DM + col] : 0.0f;
    #pragma unroll
    for (int mi = 0; mi < 4; ++mi) {
      int rbase = wm * 64 + mi * 16 + quad * 4;
      #pragma unroll
      for (int r = 0; r < 4; ++r) {
        int grow = row0 + rbase + r;
        if (grow < row_end) {
          int tk = perm[grow];
          float wt = wtok[tk];
          atomicAdd(&out[(size_t)tk * DM + col], (acc[mi][ni][r] + bv) * wt);
        }
      }
    }
  }
}

extern "C" void kernel_launch(void* const* d_in, const int* in_sizes, int n_in,
                              void* d_out, int out_size, void* d_ws, size_t ws_size,
                              hipStream_t stream)
{
  const float* x  = (const float*)d_in[0];
  const float* u  = (const float*)d_in[1];
  const float* rw = (const float*)d_in[2];
  const float* rb = (const float*)d_in[3];
  const float* w1 = (const float*)d_in[4];
  const float* b1 = (const float*)d_in[5];
  const float* w2 = (const float*)d_in[6];
  const float* b2 = (const float*)d_in[7];
  float* out = (float*)d_out;

  char* ws = (char*)d_ws;
  int*      counts    = (int*)(ws + WS_COUNTS);
  int*      cursors   = (int*)(ws + WS_CURSORS);
  int*      offsets   = (int*)(ws + WS_OFFSETS);
  float*    imp       = (float*)(ws + WS_IMP);
  int*      tile_e    = (int*)(ws + WS_TILE_E);
  int*      tile_r0   = (int*)(ws + WS_TILE_R0);
  int*      expert_of = (int*)(ws + WS_EXP);
  float*    wtok      = (float*)(ws + WS_WTOK);
  int*      perm      = (int*)(ws + WS_PERM);
  uint16_t* Xg        = (uint16_t*)(ws + WS_XG);
  uint16_t* hbuf      = (uint16_t*)(ws + WS_H);
  uint16_t* w1t       = (uint16_t*)(ws + WS_W1T);
  uint16_t* w2t       = (uint16_t*)(ws + WS_W2T);

  hipMemsetAsync(d_ws, 0, 128, stream);
  hipMemsetAsync(d_out, 0, (size_t)out_size * sizeof(float), stream);
  k_transpose_bf16<<<dim3(NH / 64, DM / 64, NE), 256, 0, stream>>>(w1, w1t, DM, NH);
  k_transpose_bf16<<<dim3(DM / 64, NH / 64, NE), 256, 0, stream>>>(w2, w2t, NH, DM);
  k_router<<<NUM_TOK / 64, 64, 0, stream>>>(x, u, rw, rb, counts, imp, expert_of, wtok);
  k_aux_offsets<<<1, 64, 0, stream>>>(counts, imp, offsets, out + (size_t)NUM_TOK * DM, tile_e, tile_r0);
  k_scatter<<<NUM_TOK / 256, 256, 0, stream>>>(expert_of, offsets, cursors, perm);
  k_gather<<<NUM_TOK, 64, 0, stream>>>(x, perm, Xg);
  k_ffn1<<<dim3(MAX_TILES, 16), 256, 0, stream>>>(Xg, w1t, b1, offsets, counts, tile_e, tile_r0, hbuf);
  k_ffn2<<<dim3(MAX_TILES, 4, KSPLIT), 256, 0, stream>>>(hbuf, w2t, b2, offsets, counts, tile_e, tile_r0, perm, wtok, out);
}

// Round 5
// 395.341 us; speedup vs baseline: 1.6154x; 1.6154x over previous
//
#include <hip/hip_runtime.h>
#include <stdint.h>
#include <math.h>

#define NUM_TOK 8192
#define DM 512
#define NE 8
#define NH 2048
#define MAX_TILES 72   // ceil-sum of per-expert 128-row tiles <= 64 + 7

typedef float f32x4 __attribute__((ext_vector_type(4)));
typedef __bf16 bf16x8 __attribute__((ext_vector_type(8)));

// ws layout (bytes)
#define WS_COUNTS   0                 // int[8]
#define WS_CURSORS  32                // int[8]
#define WS_OFFSETS  64                // int[8]
#define WS_IMP      96                // float[8]
#define WS_TILE_E   128               // int[72]
#define WS_TILE_R0  416               // int[72]
#define WS_EXP      704               // int[8192]
#define WS_WTOK     33472             // float[8192]
#define WS_PERM     66240             // int[8192]
#define WS_XG       99008             // bf16 (8192+128) x 512
#define WS_H        8618688           // bf16 (8192+128) x 2048
#define WS_W1T      42697408          // bf16 [8][2048][512]  = 16 MB
#define WS_W2T      59474624          // bf16 [8][512][2048]  = 16 MB -> ends 76,251,840

__device__ __forceinline__ uint16_t f2bf(float f) {
  union { float f; uint32_t u; } c; c.f = f;
  return (uint16_t)((c.u + 0x7FFFu + ((c.u >> 16) & 1u)) >> 16);
}

// async 16B/lane global->LDS; LDS dst = wave-uniform base + lane*16
__device__ __forceinline__ void gload_lds16(const void* g, void* l) {
  __builtin_amdgcn_global_load_lds(
      (const __attribute__((address_space(1))) uint32_t*)g,
      (__attribute__((address_space(3))) uint32_t*)l, 16, 0, 0);
}

// ---------------- router: logits (fp64), gumbel argmax, weight, counts, importance ----------------
__global__ __launch_bounds__(64) void k_router(
    const float* __restrict__ x, const float* __restrict__ u,
    const float* __restrict__ rw, const float* __restrict__ rb,
    int* __restrict__ counts, float* __restrict__ imp,
    int* __restrict__ expert_of, float* __restrict__ wtok)
{
  __shared__ float s_rw[DM * NE];
  int tid = threadIdx.x;
  for (int i = tid; i < DM * NE / 4; i += 64)
    ((float4*)s_rw)[i] = ((const float4*)rw)[i];
  __syncthreads();

  int t = blockIdx.x * 64 + tid;
  double acc[NE];
  #pragma unroll
  for (int e = 0; e < NE; ++e) acc[e] = 0.0;
  const float* xr = x + (size_t)t * DM;
  for (int d4 = 0; d4 < DM / 4; ++d4) {
    float4 xv4 = ((const float4*)xr)[d4];
    #pragma unroll
    for (int c = 0; c < 4; ++c) {
      int d = d4 * 4 + c;
      double xv = (double)((c == 0) ? xv4.x : (c == 1) ? xv4.y : (c == 2) ? xv4.z : xv4.w);
      float4 r0 = ((const float4*)s_rw)[d * 2];
      float4 r1 = ((const float4*)s_rw)[d * 2 + 1];
      acc[0] += xv * (double)r0.x;
      acc[1] += xv * (double)r0.y;
      acc[2] += xv * (double)r0.z;
      acc[3] += xv * (double)r0.w;
      acc[4] += xv * (double)r1.x;
      acc[5] += xv * (double)r1.y;
      acc[6] += xv * (double)r1.z;
      acc[7] += xv * (double)r1.w;
    }
  }
  double lg[NE];
  #pragma unroll
  for (int e = 0; e < NE; ++e) lg[e] = acc[e] + (double)rb[e];

  // gumbel-perturbed argmax (first max wins, matching jnp.argmax)
  double ybest = -1e300; int sel = 0;
  double y[NE];
  #pragma unroll
  for (int e = 0; e < NE; ++e) {
    double uv = (double)u[t * NE + e];
    double g = -log(-log(uv) + 1e-10);
    y[e] = lg[e] + g;
    if (y[e] > ybest) { ybest = y[e]; sel = e; }
  }
  double s = 0.0;
  #pragma unroll
  for (int e = 0; e < NE; ++e) s += exp(y[e] - ybest);
  double p = 1.0 / s;                    // y_soft at the selected expert
  float w = (float)((1.0 - p) + p);      // hard - sg(y_soft) + y_soft, selected entry

  expert_of[t] = sel;
  wtok[t] = w;
  atomicAdd(&counts[sel], 1);

  // softmax(logits) for importance (aux loss)
  double lm = lg[0];
  #pragma unroll
  for (int e = 1; e < NE; ++e) lm = fmax(lm, lg[e]);
  double ss = 0.0; double pr[NE];
  #pragma unroll
  for (int e = 0; e < NE; ++e) { pr[e] = exp(lg[e] - lm); ss += pr[e]; }
  double inv = 1.0 / ss;
  #pragma unroll
  for (int e = 0; e < NE; ++e) {
    float v = (float)(pr[e] * inv);
    #pragma unroll
    for (int off = 32; off; off >>= 1) v += __shfl_xor(v, off, 64);
    if (tid == 0) atomicAdd(&imp[e], v);
  }
}

// ---------------- offsets + aux loss + compact tile table ----------------
__global__ void k_aux_offsets(const int* __restrict__ counts, const float* __restrict__ imp,
                              int* __restrict__ offsets, float* __restrict__ aux_out,
                              int* __restrict__ tile_e, int* __restrict__ tile_r0)
{
  if (threadIdx.x == 0) {
    int o = 0;
    for (int e = 0; e < NE; ++e) { offsets[e] = o; o += counts[e]; }
    float a = 0.0f;
    for (int e = 0; e < NE; ++e) {
      float dv = imp[e] / 8192.0f - 0.125f;
      a += dv * dv;
    }
    aux_out[0] = a / 8.0f;
    int nt = 0;
    for (int e = 0; e < NE; ++e) {
      int ntile = (counts[e] + 127) >> 7;
      for (int j = 0; j < ntile; ++j) {
        tile_e[nt] = e;
        tile_r0[nt] = offsets[e] + j * 128;
        ++nt;
      }
    }
    for (int i = nt; i < MAX_TILES; ++i) { tile_e[i] = -1; tile_r0[i] = 0; }
  }
}

// ---------------- counting-sort scatter: perm[pos] = token ----------------
__global__ __launch_bounds__(256) void k_scatter(
    const int* __restrict__ expert_of, const int* __restrict__ offsets,
    int* __restrict__ cursors, int* __restrict__ perm)
{
  int t = blockIdx.x * 256 + threadIdx.x;
  int e = expert_of[t];
  int pos = offsets[e] + atomicAdd(&cursors[e], 1);
  perm[pos] = t;
}

// ---------------- gather x rows into sorted bf16 Xg ----------------
__global__ __launch_bounds__(64) void k_gather(
    const float* __restrict__ x, const int* __restrict__ perm, uint16_t* __restrict__ Xg)
{
  int r = blockIdx.x;
  int lane = threadIdx.x;
  int t = perm[r];
  const float4* src = (const float4*)(x + (size_t)t * DM);
  float4 a = src[lane * 2];
  float4 b = src[lane * 2 + 1];
  uint32_t p0 = (uint32_t)f2bf(a.x) | ((uint32_t)f2bf(a.y) << 16);
  uint32_t p1 = (uint32_t)f2bf(a.z) | ((uint32_t)f2bf(a.w) << 16);
  uint32_t p2 = (uint32_t)f2bf(b.x) | ((uint32_t)f2bf(b.y) << 16);
  uint32_t p3 = (uint32_t)f2bf(b.z) | ((uint32_t)f2bf(b.w) << 16);
  uint4 v = make_uint4(p0, p1, p2, p3);
  ((uint4*)(Xg + (size_t)r * DM))[lane] = v;
}

// ---------------- weight transpose+convert: src [e][K][N] f32 -> dst [e][N][K] bf16 ----------------
__global__ __launch_bounds__(256) void k_transpose_bf16(
    const float* __restrict__ src, uint16_t* __restrict__ dst, int K, int N)
{
  __shared__ float T[64][65];
  int e = blockIdx.z;
  const float* s = src + (size_t)e * K * N;
  uint16_t* d = dst + (size_t)e * K * N;
  int n0 = blockIdx.x * 64, k0 = blockIdx.y * 64;
  int tid = threadIdx.x;
  int tr = tid >> 4;
  int tc = (tid & 15) * 4;
  #pragma unroll
  for (int p = 0; p < 4; ++p) {
    int k = tr + p * 16;
    float4 v = *(const float4*)(s + (size_t)(k0 + k) * N + n0 + tc);
    T[k][tc] = v.x; T[k][tc + 1] = v.y; T[k][tc + 2] = v.z; T[k][tc + 3] = v.w;
  }
  __syncthreads();
  #pragma unroll
  for (int p = 0; p < 2; ++p) {
    int slot = p * 256 + tid;
    int n = slot >> 3;
    int c = (slot & 7) * 8;
    uint16_t tmp[8];
    #pragma unroll
    for (int j = 0; j < 8; ++j) tmp[j] = f2bf(T[c + j][n]);
    *(uint4*)(d + (size_t)(n0 + n) * K + k0 + c) = *(uint4*)tmp;
  }
}

// ---------------- layer 1: h = gelu(Xg @ w1t[e]^T + b1[e]) ----------------
// grid (MAX_TILES, 16). Async global_load_lds staging, XOR-swizzled LDS layout:
// LDS[row][c] holds global chunk (c ^ (row&7)); reader applies the same XOR.
__global__ __launch_bounds__(256) void k_ffn1(
    const uint16_t* __restrict__ Xg, const uint16_t* __restrict__ w1t,
    const float* __restrict__ b1,
    const int* __restrict__ offsets, const int* __restrict__ counts,
    const int* __restrict__ tile_e, const int* __restrict__ tile_r0,
    uint16_t* __restrict__ hbuf)
{
  int e = tile_e[blockIdx.x];
  if (e < 0) return;
  int row0 = tile_r0[blockIdx.x];
  int row_end = offsets[e] + counts[e];
  int n0 = blockIdx.y * 128;
  const uint16_t* Bt = w1t + (size_t)e * DM * NH;   // [2048][512] bf16

  __shared__ uint16_t As[128 * 64];
  __shared__ uint16_t Bs[128 * 64];

  int tid = threadIdx.x;
  int lane = tid & 63, wid = tid >> 6;
  int wm = wid >> 1, wn = wid & 1;
  int l16 = lane & 15, quad = lane >> 4;

  // staging: per wave 4 A-chunks + 4 B-chunks of 8 rows x 64 cols each
  int lrow = lane >> 3;                    // 0..7 row within chunk
  int lsw  = (lane & 7) ^ lrow;            // swizzled global chunk this lane fetches
  const uint16_t *ga[4], *gb[4];
  uint16_t *la[4], *lb[4];
  #pragma unroll
  for (int j = 0; j < 4; ++j) {
    int r = wid * 32 + j * 8;
    ga[j] = Xg + (size_t)(row0 + r + lrow) * DM + lsw * 8;
    gb[j] = Bt + (size_t)(n0 + r + lrow) * DM + lsw * 8;
    la[j] = As + r * 64;
    lb[j] = Bs + r * 64;
  }

  f32x4 acc[4][4] = {};

  for (int k0 = 0; k0 < DM; k0 += 64) {
    #pragma unroll
    for (int j = 0; j < 4; ++j) { gload_lds16(ga[j], la[j]); ga[j] += 64; }
    #pragma unroll
    for (int j = 0; j < 4; ++j) { gload_lds16(gb[j], lb[j]); gb[j] += 64; }
    __syncthreads();
    #pragma unroll
    for (int ks = 0; ks < 2; ++ks) {
      bf16x8 a[4], b[4];
      #pragma unroll
      for (int mi = 0; mi < 4; ++mi) {
        int row = wm * 64 + mi * 16 + l16;
        a[mi] = *(const bf16x8*)(As + row * 64 + (((ks * 4 + quad) ^ (l16 & 7)) * 8));
      }
      #pragma unroll
      for (int ni = 0; ni < 4; ++ni) {
        int row = wn * 64 + ni * 16 + l16;
        b[ni] = *(const bf16x8*)(Bs + row * 64 + (((ks * 4 + quad) ^ (l16 & 7)) * 8));
      }
      #pragma unroll
      for (int mi = 0; mi < 4; ++mi)
        #pragma unroll
        for (int ni = 0; ni < 4; ++ni)
          acc[mi][ni] = __builtin_amdgcn_mfma_f32_16x16x32_bf16(a[mi], b[ni], acc[mi][ni], 0, 0, 0);
    }
    __syncthreads();
  }

  #pragma unroll
  for (int ni = 0; ni < 4; ++ni) {
    int col = n0 + wn * 64 + ni * 16 + l16;
    float bv = b1[e * NH + col];
    #pragma unroll
    for (int mi = 0; mi < 4; ++mi) {
      int rbase = wm * 64 + mi * 16 + quad * 4;
      #pragma unroll
      for (int r = 0; r < 4; ++r) {
        int grow = row0 + rbase + r;
        if (grow < row_end) {
          float v = acc[mi][ni][r] + bv;
          float gl = 0.5f * v * (1.0f + erff(v * 0.70710678118654752440f));
          hbuf[(size_t)grow * NH + col] = f2bf(gl);
        }
      }
    }
  }
}

// ---------------- layer 2: out[token] = (h @ w2t[e]^T + b2[e]) * w_token ----------------
// grid (MAX_TILES, 4). Same async-staging structure, K = 2048 (32 iters).
__global__ __launch_bounds__(256) void k_ffn2(
    const uint16_t* __restrict__ hbuf, const uint16_t* __restrict__ w2t,
    const float* __restrict__ b2,
    const int* __restrict__ offsets, const int* __restrict__ counts,
    const int* __restrict__ tile_e, const int* __restrict__ tile_r0,
    const int* __restrict__ perm, const float* __restrict__ wtok,
    float* __restrict__ out)
{
  int e = tile_e[blockIdx.x];
  if (e < 0) return;
  int row0 = tile_r0[blockIdx.x];
  int row_end = offsets[e] + counts[e];
  int n0 = blockIdx.y * 128;
  const uint16_t* Bt = w2t + (size_t)e * NH * DM;   // [512][2048] bf16

  __shared__ uint16_t As[128 * 64];
  __shared__ uint16_t Bs[128 * 64];

  int tid = threadIdx.x;
  int lane = tid & 63, wid = tid >> 6;
  int wm = wid >> 1, wn = wid & 1;
  int l16 = lane & 15, quad = lane >> 4;

  int lrow = lane >> 3;
  int lsw  = (lane & 7) ^ lrow;
  const uint16_t *ga[4], *gb[4];
  uint16_t *la[4], *lb[4];
  #pragma unroll
  for (int j = 0; j < 4; ++j) {
    int r = wid * 32 + j * 8;
    ga[j] = hbuf + (size_t)(row0 + r + lrow) * NH + lsw * 8;
    gb[j] = Bt + (size_t)(n0 + r + lrow) * NH + lsw * 8;
    la[j] = As + r * 64;
    lb[j] = Bs + r * 64;
  }

  f32x4 acc[4][4] = {};

  for (int k0 = 0; k0 < NH; k0 += 64) {
    #pragma unroll
    for (int j = 0; j < 4; ++j) { gload_lds16(ga[j], la[j]); ga[j] += 64; }
    #pragma unroll
    for (int j = 0; j < 4; ++j) { gload_lds16(gb[j], lb[j]); gb[j] += 64; }
    __syncthreads();
    #pragma unroll
    for (int ks = 0; ks < 2; ++ks) {
      bf16x8 a[4], b[4];
      #pragma unroll
      for (int mi = 0; mi < 4; ++mi) {
        int row = wm * 64 + mi * 16 + l16;
        a[mi] = *(const bf16x8*)(As + row * 64 + (((ks * 4 + quad) ^ (l16 & 7)) * 8));
      }
      #pragma unroll
      for (int ni = 0; ni < 4; ++ni) {
        int row = wn * 64 + ni * 16 + l16;
        b[ni] = *(const bf16x8*)(Bs + row * 64 + (((ks * 4 + quad) ^ (l16 & 7)) * 8));
      }
      #pragma unroll
      for (int mi = 0; mi < 4; ++mi)
        #pragma unroll
        for (int ni = 0; ni < 4; ++ni)
          acc[mi][ni] = __builtin_amdgcn_mfma_f32_16x16x32_bf16(a[mi], b[ni], acc[mi][ni], 0, 0, 0);
    }
    __syncthreads();
  }

  #pragma unroll
  for (int ni = 0; ni < 4; ++ni) {
    int col = n0 + wn * 64 + ni * 16 + l16;
    float bv = b2[e * DM + col];
    #pragma unroll
    for (int mi = 0; mi < 4; ++mi) {
      int rbase = wm * 64 + mi * 16 + quad * 4;
      #pragma unroll
      for (int r = 0; r < 4; ++r) {
        int grow = row0 + rbase + r;
        if (grow < row_end) {
          int tk = perm[grow];
          float wt = wtok[tk];
          out[(size_t)tk * DM + col] = (acc[mi][ni][r] + bv) * wt;
        }
      }
    }
  }
}

extern "C" void kernel_launch(void* const* d_in, const int* in_sizes, int n_in,
                              void* d_out, int out_size, void* d_ws, size_t ws_size,
                              hipStream_t stream)
{
  const float* x  = (const float*)d_in[0];
  const float* u  = (const float*)d_in[1];
  const float* rw = (const float*)d_in[2];
  const float* rb = (const float*)d_in[3];
  const float* w1 = (const float*)d_in[4];
  const float* b1 = (const float*)d_in[5];
  const float* w2 = (const float*)d_in[6];
  const float* b2 = (const float*)d_in[7];
  float* out = (float*)d_out;

  char* ws = (char*)d_ws;
  int*      counts    = (int*)(ws + WS_COUNTS);
  int*      cursors   = (int*)(ws + WS_CURSORS);
  int*      offsets   = (int*)(ws + WS_OFFSETS);
  float*    imp       = (float*)(ws + WS_IMP);
  int*      tile_e    = (int*)(ws + WS_TILE_E);
  int*      tile_r0   = (int*)(ws + WS_TILE_R0);
  int*      expert_of = (int*)(ws + WS_EXP);
  float*    wtok      = (float*)(ws + WS_WTOK);
  int*      perm      = (int*)(ws + WS_PERM);
  uint16_t* Xg        = (uint16_t*)(ws + WS_XG);
  uint16_t* hbuf      = (uint16_t*)(ws + WS_H);
  uint16_t* w1t       = (uint16_t*)(ws + WS_W1T);
  uint16_t* w2t       = (uint16_t*)(ws + WS_W2T);

  hipMemsetAsync(d_ws, 0, 128, stream);
  k_transpose_bf16<<<dim3(NH / 64, DM / 64, NE), 256, 0, stream>>>(w1, w1t, DM, NH);
  k_transpose_bf16<<<dim3(DM / 64, NH / 64, NE), 256, 0, stream>>>(w2, w2t, NH, DM);
  k_router<<<NUM_TOK / 64, 64, 0, stream>>>(x, u, rw, rb, counts, imp, expert_of, wtok);
  k_aux_offsets<<<1, 64, 0, stream>>>(counts, imp, offsets, out + (size_t)NUM_TOK * DM, tile_e, tile_r0);
  k_scatter<<<NUM_TOK / 256, 256, 0, stream>>>(expert_of, offsets, cursors, perm);
  k_gather<<<NUM_TOK, 64, 0, stream>>>(x, perm, Xg);
  k_ffn1<<<dim3(MAX_TILES, 16), 256, 0, stream>>>(Xg, w1t, b1, offsets, counts, tile_e, tile_r0, hbuf);
  k_ffn2<<<dim3(MAX_TILES, 4), 256, 0, stream>>>(hbuf, w2t, b2, offsets, counts, tile_e, tile_r0, perm, wtok, out);
}

// Round 6
// 386.047 us; speedup vs baseline: 1.6543x; 1.0241x over previous
//
#include <hip/hip_runtime.h>
#include <stdint.h>
#include <math.h>

#define NUM_TOK 8192
#define DM 512
#define NE 8
#define NH 2048
#define MAX_TILES 72   // ceil-sum of per-expert 128-row tiles <= 64 + 7

typedef float f32x4 __attribute__((ext_vector_type(4)));
typedef __bf16 bf16x8 __attribute__((ext_vector_type(8)));

// ws layout (bytes)
#define WS_COUNTS   0                 // int[8]
#define WS_CURSORS  32                // int[8]
#define WS_OFFSETS  64                // int[8]
#define WS_IMP      96                // float[8]
#define WS_TILE_E   128               // int[72]
#define WS_TILE_R0  416               // int[72]
#define WS_EXP      704               // int[8192]
#define WS_WTOK     33472             // float[8192]
#define WS_PERM     66240             // int[8192]
#define WS_XG       99008             // bf16 (8192+128) x 512
#define WS_H        8618688           // bf16 (8192+128) x 2048
#define WS_W1T      42697408          // bf16 [8][2048][512]  = 16 MB
#define WS_W2T      59474624          // bf16 [8][512][2048]  = 16 MB -> ends 76,251,840

__device__ __forceinline__ uint16_t f2bf(float f) {
  union { float f; uint32_t u; } c; c.f = f;
  return (uint16_t)((c.u + 0x7FFFu + ((c.u >> 16) & 1u)) >> 16);
}

// branch-free gelu: v * sigmoid(2*0.7978845608*(v + 0.044715 v^3))
// max abs err vs exact ~5e-4, negligible downstream of bf16 storage.
__device__ __forceinline__ float gelu_fast(float v) {
  float z = 1.5957691216f * v * (1.0f + 0.044715f * v * v);
  float em = __expf(-z);
  return v / (1.0f + em);
}

// async 16B/lane global->LDS; LDS dst = wave-uniform base + lane*16
__device__ __forceinline__ void gload_lds16(const void* g, void* l) {
  __builtin_amdgcn_global_load_lds(
      (const __attribute__((address_space(1))) uint32_t*)g,
      (__attribute__((address_space(3))) uint32_t*)l, 16, 0, 0);
}

// ---------------- router: logits (fp64), gumbel argmax, weight, counts, importance ----------------
__global__ __launch_bounds__(64) void k_router(
    const float* __restrict__ x, const float* __restrict__ u,
    const float* __restrict__ rw, const float* __restrict__ rb,
    int* __restrict__ counts, float* __restrict__ imp,
    int* __restrict__ expert_of, float* __restrict__ wtok)
{
  __shared__ float s_rw[DM * NE];
  int tid = threadIdx.x;
  for (int i = tid; i < DM * NE / 4; i += 64)
    ((float4*)s_rw)[i] = ((const float4*)rw)[i];
  __syncthreads();

  int t = blockIdx.x * 64 + tid;
  double acc[NE];
  #pragma unroll
  for (int e = 0; e < NE; ++e) acc[e] = 0.0;
  const float* xr = x + (size_t)t * DM;
  for (int d4 = 0; d4 < DM / 4; ++d4) {
    float4 xv4 = ((const float4*)xr)[d4];
    #pragma unroll
    for (int c = 0; c < 4; ++c) {
      int d = d4 * 4 + c;
      double xv = (double)((c == 0) ? xv4.x : (c == 1) ? xv4.y : (c == 2) ? xv4.z : xv4.w);
      float4 r0 = ((const float4*)s_rw)[d * 2];
      float4 r1 = ((const float4*)s_rw)[d * 2 + 1];
      acc[0] += xv * (double)r0.x;
      acc[1] += xv * (double)r0.y;
      acc[2] += xv * (double)r0.z;
      acc[3] += xv * (double)r0.w;
      acc[4] += xv * (double)r1.x;
      acc[5] += xv * (double)r1.y;
      acc[6] += xv * (double)r1.z;
      acc[7] += xv * (double)r1.w;
    }
  }
  double lg[NE];
  #pragma unroll
  for (int e = 0; e < NE; ++e) lg[e] = acc[e] + (double)rb[e];

  // gumbel-perturbed argmax (first max wins, matching jnp.argmax)
  double ybest = -1e300; int sel = 0;
  double y[NE];
  #pragma unroll
  for (int e = 0; e < NE; ++e) {
    double uv = (double)u[t * NE + e];
    double g = -log(-log(uv) + 1e-10);
    y[e] = lg[e] + g;
    if (y[e] > ybest) { ybest = y[e]; sel = e; }
  }
  double s = 0.0;
  #pragma unroll
  for (int e = 0; e < NE; ++e) s += exp(y[e] - ybest);
  double p = 1.0 / s;                    // y_soft at the selected expert
  float w = (float)((1.0 - p) + p);      // hard - sg(y_soft) + y_soft, selected entry

  expert_of[t] = sel;
  wtok[t] = w;
  atomicAdd(&counts[sel], 1);

  // softmax(logits) for importance (aux loss)
  double lm = lg[0];
  #pragma unroll
  for (int e = 1; e < NE; ++e) lm = fmax(lm, lg[e]);
  double ss = 0.0; double pr[NE];
  #pragma unroll
  for (int e = 0; e < NE; ++e) { pr[e] = exp(lg[e] - lm); ss += pr[e]; }
  double inv = 1.0 / ss;
  #pragma unroll
  for (int e = 0; e < NE; ++e) {
    float v = (float)(pr[e] * inv);
    #pragma unroll
    for (int off = 32; off; off >>= 1) v += __shfl_xor(v, off, 64);
    if (tid == 0) atomicAdd(&imp[e], v);
  }
}

// ---------------- offsets + aux loss + compact tile table ----------------
__global__ void k_aux_offsets(const int* __restrict__ counts, const float* __restrict__ imp,
                              int* __restrict__ offsets, float* __restrict__ aux_out,
                              int* __restrict__ tile_e, int* __restrict__ tile_r0)
{
  if (threadIdx.x == 0) {
    int o = 0;
    for (int e = 0; e < NE; ++e) { offsets[e] = o; o += counts[e]; }
    float a = 0.0f;
    for (int e = 0; e < NE; ++e) {
      float dv = imp[e] / 8192.0f - 0.125f;
      a += dv * dv;
    }
    aux_out[0] = a / 8.0f;
    int nt = 0;
    for (int e = 0; e < NE; ++e) {
      int ntile = (counts[e] + 127) >> 7;
      for (int j = 0; j < ntile; ++j) {
        tile_e[nt] = e;
        tile_r0[nt] = offsets[e] + j * 128;
        ++nt;
      }
    }
    for (int i = nt; i < MAX_TILES; ++i) { tile_e[i] = -1; tile_r0[i] = 0; }
  }
}

// ---------------- counting-sort scatter: perm[pos] = token ----------------
__global__ __launch_bounds__(256) void k_scatter(
    const int* __restrict__ expert_of, const int* __restrict__ offsets,
    int* __restrict__ cursors, int* __restrict__ perm)
{
  int t = blockIdx.x * 256 + threadIdx.x;
  int e = expert_of[t];
  int pos = offsets[e] + atomicAdd(&cursors[e], 1);
  perm[pos] = t;
}

// ---------------- gather x rows into sorted bf16 Xg ----------------
__global__ __launch_bounds__(64) void k_gather(
    const float* __restrict__ x, const int* __restrict__ perm, uint16_t* __restrict__ Xg)
{
  int r = blockIdx.x;
  int lane = threadIdx.x;
  int t = perm[r];
  const float4* src = (const float4*)(x + (size_t)t * DM);
  float4 a = src[lane * 2];
  float4 b = src[lane * 2 + 1];
  uint32_t p0 = (uint32_t)f2bf(a.x) | ((uint32_t)f2bf(a.y) << 16);
  uint32_t p1 = (uint32_t)f2bf(a.z) | ((uint32_t)f2bf(a.w) << 16);
  uint32_t p2 = (uint32_t)f2bf(b.x) | ((uint32_t)f2bf(b.y) << 16);
  uint32_t p3 = (uint32_t)f2bf(b.z) | ((uint32_t)f2bf(b.w) << 16);
  uint4 v = make_uint4(p0, p1, p2, p3);
  ((uint4*)(Xg + (size_t)r * DM))[lane] = v;
}

// ---------------- weight transpose+convert: src [e][K][N] f32 -> dst [e][N][K] bf16 ----------------
__global__ __launch_bounds__(256) void k_transpose_bf16(
    const float* __restrict__ src, uint16_t* __restrict__ dst, int K, int N)
{
  __shared__ float T[64][65];
  int e = blockIdx.z;
  const float* s = src + (size_t)e * K * N;
  uint16_t* d = dst + (size_t)e * K * N;
  int n0 = blockIdx.x * 64, k0 = blockIdx.y * 64;
  int tid = threadIdx.x;
  int tr = tid >> 4;
  int tc = (tid & 15) * 4;
  #pragma unroll
  for (int p = 0; p < 4; ++p) {
    int k = tr + p * 16;
    float4 v = *(const float4*)(s + (size_t)(k0 + k) * N + n0 + tc);
    T[k][tc] = v.x; T[k][tc + 1] = v.y; T[k][tc + 2] = v.z; T[k][tc + 3] = v.w;
  }
  __syncthreads();
  #pragma unroll
  for (int p = 0; p < 2; ++p) {
    int slot = p * 256 + tid;
    int n = slot >> 3;
    int c = (slot & 7) * 8;
    uint16_t tmp[8];
    #pragma unroll
    for (int j = 0; j < 8; ++j) tmp[j] = f2bf(T[c + j][n]);
    *(uint4*)(d + (size_t)(n0 + n) * K + k0 + c) = *(uint4*)tmp;
  }
}

// ---------------- layer 1: h = gelu(Xg @ w1t[e]^T + b1[e]) ----------------
// grid (MAX_TILES, 16). Async global_load_lds staging, XOR-swizzled LDS layout.
__global__ __launch_bounds__(256) void k_ffn1(
    const uint16_t* __restrict__ Xg, const uint16_t* __restrict__ w1t,
    const float* __restrict__ b1,
    const int* __restrict__ offsets, const int* __restrict__ counts,
    const int* __restrict__ tile_e, const int* __restrict__ tile_r0,
    uint16_t* __restrict__ hbuf)
{
  int e = tile_e[blockIdx.x];
  if (e < 0) return;
  int row0 = tile_r0[blockIdx.x];
  int row_end = offsets[e] + counts[e];
  int n0 = blockIdx.y * 128;
  const uint16_t* Bt = w1t + (size_t)e * DM * NH;   // [2048][512] bf16

  __shared__ uint16_t As[128 * 64];
  __shared__ uint16_t Bs[128 * 64];

  int tid = threadIdx.x;
  int lane = tid & 63, wid = tid >> 6;
  int wm = wid >> 1, wn = wid & 1;
  int l16 = lane & 15, quad = lane >> 4;

  int lrow = lane >> 3;                    // 0..7 row within chunk
  int lsw  = (lane & 7) ^ lrow;            // swizzled global chunk this lane fetches
  const uint16_t *ga[4], *gb[4];
  uint16_t *la[4], *lb[4];
  #pragma unroll
  for (int j = 0; j < 4; ++j) {
    int r = wid * 32 + j * 8;
    ga[j] = Xg + (size_t)(row0 + r + lrow) * DM + lsw * 8;
    gb[j] = Bt + (size_t)(n0 + r + lrow) * DM + lsw * 8;
    la[j] = As + r * 64;
    lb[j] = Bs + r * 64;
  }

  f32x4 acc[4][4] = {};

  for (int k0 = 0; k0 < DM; k0 += 64) {
    #pragma unroll
    for (int j = 0; j < 4; ++j) { gload_lds16(ga[j], la[j]); ga[j] += 64; }
    #pragma unroll
    for (int j = 0; j < 4; ++j) { gload_lds16(gb[j], lb[j]); gb[j] += 64; }
    __syncthreads();
    #pragma unroll
    for (int ks = 0; ks < 2; ++ks) {
      bf16x8 a[4], b[4];
      #pragma unroll
      for (int mi = 0; mi < 4; ++mi) {
        int row = wm * 64 + mi * 16 + l16;
        a[mi] = *(const bf16x8*)(As + row * 64 + (((ks * 4 + quad) ^ (l16 & 7)) * 8));
      }
      #pragma unroll
      for (int ni = 0; ni < 4; ++ni) {
        int row = wn * 64 + ni * 16 + l16;
        b[ni] = *(const bf16x8*)(Bs + row * 64 + (((ks * 4 + quad) ^ (l16 & 7)) * 8));
      }
      #pragma unroll
      for (int mi = 0; mi < 4; ++mi)
        #pragma unroll
        for (int ni = 0; ni < 4; ++ni)
          acc[mi][ni] = __builtin_amdgcn_mfma_f32_16x16x32_bf16(a[mi], b[ni], acc[mi][ni], 0, 0, 0);
    }
    __syncthreads();
  }

  #pragma unroll
  for (int ni = 0; ni < 4; ++ni) {
    int col = n0 + wn * 64 + ni * 16 + l16;
    float bv = b1[e * NH + col];
    #pragma unroll
    for (int mi = 0; mi < 4; ++mi) {
      int rbase = wm * 64 + mi * 16 + quad * 4;
      #pragma unroll
      for (int r = 0; r < 4; ++r) {
        int grow = row0 + rbase + r;
        if (grow < row_end) {
          float v = acc[mi][ni][r] + bv;
          hbuf[(size_t)grow * NH + col] = f2bf(gelu_fast(v));
        }
      }
    }
  }
}

// ---------------- layer 2: out[token] = (h @ w2t[e]^T + b2[e]) * w_token ----------------
// grid (MAX_TILES, 8): 128x64 tiles for occupancy (576 blocks). LDS 24 KB.
__global__ __launch_bounds__(256) void k_ffn2(
    const uint16_t* __restrict__ hbuf, const uint16_t* __restrict__ w2t,
    const float* __restrict__ b2,
    const int* __restrict__ offsets, const int* __restrict__ counts,
    const int* __restrict__ tile_e, const int* __restrict__ tile_r0,
    const int* __restrict__ perm, const float* __restrict__ wtok,
    float* __restrict__ out)
{
  int e = tile_e[blockIdx.x];
  if (e < 0) return;
  int row0 = tile_r0[blockIdx.x];
  int row_end = offsets[e] + counts[e];
  int n0 = blockIdx.y * 64;
  const uint16_t* Bt = w2t + (size_t)e * NH * DM;   // [512][2048] bf16

  __shared__ uint16_t As[128 * 64];
  __shared__ uint16_t Bs[64 * 64];

  int tid = threadIdx.x;
  int lane = tid & 63, wid = tid >> 6;
  int wm = wid >> 1, wn = wid & 1;
  int l16 = lane & 15, quad = lane >> 4;

  int lrow = lane >> 3;
  int lsw  = (lane & 7) ^ lrow;
  const uint16_t *ga[4], *gb[2];
  uint16_t *la[4], *lb[2];
  #pragma unroll
  for (int j = 0; j < 4; ++j) {
    int r = wid * 32 + j * 8;
    ga[j] = hbuf + (size_t)(row0 + r + lrow) * NH + lsw * 8;
    la[j] = As + r * 64;
  }
  #pragma unroll
  for (int j = 0; j < 2; ++j) {
    int r = wid * 16 + j * 8;
    gb[j] = Bt + (size_t)(n0 + r + lrow) * NH + lsw * 8;
    lb[j] = Bs + r * 64;
  }

  f32x4 acc[4][2] = {};

  for (int k0 = 0; k0 < NH; k0 += 64) {
    #pragma unroll
    for (int j = 0; j < 4; ++j) { gload_lds16(ga[j], la[j]); ga[j] += 64; }
    #pragma unroll
    for (int j = 0; j < 2; ++j) { gload_lds16(gb[j], lb[j]); gb[j] += 64; }
    __syncthreads();
    #pragma unroll
    for (int ks = 0; ks < 2; ++ks) {
      bf16x8 a[4], b[2];
      #pragma unroll
      for (int mi = 0; mi < 4; ++mi) {
        int row = wm * 64 + mi * 16 + l16;
        a[mi] = *(const bf16x8*)(As + row * 64 + (((ks * 4 + quad) ^ (l16 & 7)) * 8));
      }
      #pragma unroll
      for (int ni = 0; ni < 2; ++ni) {
        int row = wn * 32 + ni * 16 + l16;
        b[ni] = *(const bf16x8*)(Bs + row * 64 + (((ks * 4 + quad) ^ (l16 & 7)) * 8));
      }
      #pragma unroll
      for (int mi = 0; mi < 4; ++mi)
        #pragma unroll
        for (int ni = 0; ni < 2; ++ni)
          acc[mi][ni] = __builtin_amdgcn_mfma_f32_16x16x32_bf16(a[mi], b[ni], acc[mi][ni], 0, 0, 0);
    }
    __syncthreads();
  }

  #pragma unroll
  for (int ni = 0; ni < 2; ++ni) {
    int col = n0 + wn * 32 + ni * 16 + l16;
    float bv = b2[e * DM + col];
    #pragma unroll
    for (int mi = 0; mi < 4; ++mi) {
      int rbase = wm * 64 + mi * 16 + quad * 4;
      #pragma unroll
      for (int r = 0; r < 4; ++r) {
        int grow = row0 + rbase + r;
        if (grow < row_end) {
          int tk = perm[grow];
          float wt = wtok[tk];
          out[(size_t)tk * DM + col] = (acc[mi][ni][r] + bv) * wt;
        }
      }
    }
  }
}

extern "C" void kernel_launch(void* const* d_in, const int* in_sizes, int n_in,
                              void* d_out, int out_size, void* d_ws, size_t ws_size,
                              hipStream_t stream)
{
  const float* x  = (const float*)d_in[0];
  const float* u  = (const float*)d_in[1];
  const float* rw = (const float*)d_in[2];
  const float* rb = (const float*)d_in[3];
  const float* w1 = (const float*)d_in[4];
  const float* b1 = (const float*)d_in[5];
  const float* w2 = (const float*)d_in[6];
  const float* b2 = (const float*)d_in[7];
  float* out = (float*)d_out;

  char* ws = (char*)d_ws;
  int*      counts    = (int*)(ws + WS_COUNTS);
  int*      cursors   = (int*)(ws + WS_CURSORS);
  int*      offsets   = (int*)(ws + WS_OFFSETS);
  float*    imp       = (float*)(ws + WS_IMP);
  int*      tile_e    = (int*)(ws + WS_TILE_E);
  int*      tile_r0   = (int*)(ws + WS_TILE_R0);
  int*      expert_of = (int*)(ws + WS_EXP);
  float*    wtok      = (float*)(ws + WS_WTOK);
  int*      perm      = (int*)(ws + WS_PERM);
  uint16_t* Xg        = (uint16_t*)(ws + WS_XG);
  uint16_t* hbuf      = (uint16_t*)(ws + WS_H);
  uint16_t* w1t       = (uint16_t*)(ws + WS_W1T);
  uint16_t* w2t       = (uint16_t*)(ws + WS_W2T);

  hipMemsetAsync(d_ws, 0, 128, stream);
  k_transpose_bf16<<<dim3(NH / 64, DM / 64, NE), 256, 0, stream>>>(w1, w1t, DM, NH);
  k_transpose_bf16<<<dim3(DM / 64, NH / 64, NE), 256, 0, stream>>>(w2, w2t, NH, DM);
  k_router<<<NUM_TOK / 64, 64, 0, stream>>>(x, u, rw, rb, counts, imp, expert_of, wtok);
  k_aux_offsets<<<1, 64, 0, stream>>>(counts, imp, offsets, out + (size_t)NUM_TOK * DM, tile_e, tile_r0);
  k_scatter<<<NUM_TOK / 256, 256, 0, stream>>>(expert_of, offsets, cursors, perm);
  k_gather<<<NUM_TOK, 64, 0, stream>>>(x, perm, Xg);
  k_ffn1<<<dim3(MAX_TILES, 16), 256, 0, stream>>>(Xg, w1t, b1, offsets, counts, tile_e, tile_r0, hbuf);
  k_ffn2<<<dim3(MAX_TILES, 8), 256, 0, stream>>>(hbuf, w2t, b2, offsets, counts, tile_e, tile_r0, perm, wtok, out);
}